// Round 7
// baseline (188.596 us; speedup 1.0000x reference)
//
#include <hip/hip_runtime.h>

#define HH 8
#define TT 4096
#define DD 128
#define NKT 128              // 32-key tiles per head
#define PS 36                // P row stride in shorts (72 B rows)
#define NEG_BIG (-3.0e38f)

// ws (shorts): Khi[8.4MB] | Klo[8.4MB] | Vt[8.4MB]
#define HEAD_FRAG_SHORTS ((size_t)NKT * 8 * 512)

typedef __attribute__((ext_vector_type(8)))  short short8;
typedef __attribute__((ext_vector_type(16))) float float16;

__device__ __forceinline__ short bf16_rne(float x) {
    unsigned u = __float_as_uint(x);
    return (short)((u + 0x7fffu + ((u >> 16) & 1u)) >> 16);
}
__device__ __forceinline__ float bf16_f(short s) {
    return __uint_as_float(((unsigned)(unsigned short)s) << 16);
}

// ---------------- prep: fp32 K,V -> bf16 hi/lo fragments (verified, unchanged) ----------------
__global__ __launch_bounds__(256) void prep_kernel(
    const float* __restrict__ k, const float* __restrict__ v,
    short* __restrict__ khi, short* __restrict__ klo, short* __restrict__ vt)
{
    const int h = blockIdx.x, kt = blockIdx.y, t = threadIdx.x;
    __shared__ float Vs[32][132];

    #pragma unroll
    for (int it = 0; it < 4; ++it) {               // stage V tile 32 keys x 128 dims
        const int f = t + it * 256, j = f >> 5, c = f & 31;
        *(float4*)&Vs[j][c * 4] =
            *(const float4*)(v + ((size_t)(h * TT + kt * 32 + j)) * DD + c * 4);
    }
    // K fragments: B[n=key m][k-dim = ks*16 + hf*8 + e]
    #pragma unroll
    for (int it = 0; it < 2; ++it) {
        const int idx = t + it * 256;
        const int ks = idx >> 6, ln = idx & 63, m = ln & 31, hf = ln >> 5;
        const float* src = k + ((size_t)(h * TT + kt * 32 + m)) * DD + ks * 16 + hf * 8;
        const float4 a = *(const float4*)src;
        const float4 b = *(const float4*)(src + 4);
        const float f8[8] = {a.x, a.y, a.z, a.w, b.x, b.y, b.z, b.w};
        short8 hi8, lo8;
        #pragma unroll
        for (int e = 0; e < 8; ++e) {
            const short hi_ = bf16_rne(f8[e]);
            hi8[e] = hi_;
            lo8[e] = bf16_rne(f8[e] - bf16_f(hi_));
        }
        const size_t off = ((size_t)((h * NKT + kt) * 8 + ks)) * 512 + ln * 8;
        *(short8*)(khi + off) = hi8;
        *(short8*)(klo + off) = lo8;
    }
    __syncthreads();
    // V fragments: B[n=dim nt*32+m][k-key = ks2*16 + hf*8 + e]
    #pragma unroll
    for (int it = 0; it < 2; ++it) {
        const int idx = t + it * 256;
        const int nt = idx >> 7, ks2 = (idx >> 6) & 1, ln = idx & 63;
        const int m = ln & 31, hf = ln >> 5, n = nt * 32 + m;
        short8 o;
        #pragma unroll
        for (int e = 0; e < 8; ++e)
            o[e] = bf16_rne(Vs[ks2 * 16 + hf * 8 + e][n]);
        *(short8*)(vt + ((size_t)(((h * NKT + kt) * 4 + nt) * 2 + ks2)) * 512 + ln * 8) = o;
    }
}

// ------- attention: 4-wave split-K, Q in LDS, dual-chain QK, K reg-prefetch -------
// Round-6 (112.4µs, verified) + ONE change: cross-tile K register prefetch.
// K hi/lo fragments live in khb[8]/klb[8] (64 regs); after QK consumes them,
// the NEXT tile's loads are issued into the same names — their ~200cy L2
// latency hides under softmax+PV instead of stalling the next QK head.
// Peak liveness ~205 regs < 256 (2 waves/SIMD cap); spill signature =
// WRITE_SIZE >> 16MB. Last iteration reloads its own tile (clamped, unused).
__global__ __launch_bounds__(256, 2) void attn_kernel(
    const float* __restrict__ q,
    const short* __restrict__ khi, const short* __restrict__ klo,
    const short* __restrict__ vt, float* __restrict__ out)
{
    const int h = blockIdx.x;                          // head -> XCD L2 pinning
    const int g = (int)(gridDim.y - 1) - (int)blockIdx.y;  // big row-tiles first
    const int growb = g * 32;
    const int t = threadIdx.x, w = t >> 6, ln = t & 63, m = ln & 31, hf = ln >> 5;

    // qf lifetime: staging + kt loop. oc lifetime: combine (after barrier). Union ok.
    __shared__ union {
        short qf[2][16][32][8];                        // 16 KB [hi/lo][ks*2+hf][m][e]
        float oc[4][32][36];                           // 18.4 KB combine chunks
    } U;
    __shared__ short Pl[4][32][PS];                    // wave-private P slabs (9.2 KB)
    __shared__ float Lw[4][32];
    __shared__ float Mw[4];

    const short* khiH = khi + (size_t)h * HEAD_FRAG_SHORTS;
    const short* kloH = klo + (size_t)h * HEAD_FRAG_SHORTS;
    const short* vtH  = vt  + (size_t)h * HEAD_FRAG_SHORTS;

    // ---- stage Q (32 rows) as bf16 hi/lo A-fragments into LDS (once per block)
    #pragma unroll
    for (int it = 0; it < 2; ++it) {
        const int idx = t + it * 256;                  // 512 fragments: ks*2*32 + hf*32 + m
        const int ks = idx >> 6, l2 = idx & 63, mm = l2 & 31, hh = l2 >> 5;
        const float* src = q + ((size_t)(h * TT + growb + mm)) * DD + ks * 16 + hh * 8;
        const float4 a = *(const float4*)src;
        const float4 b = *(const float4*)(src + 4);
        const float f8[8] = {a.x, a.y, a.z, a.w, b.x, b.y, b.z, b.w};
        short8 hi8, lo8;
        #pragma unroll
        for (int e = 0; e < 8; ++e) {
            const short hi_ = bf16_rne(f8[e]);
            hi8[e] = hi_;
            lo8[e] = bf16_rne(f8[e] - bf16_f(hi_));
        }
        *(short8*)&U.qf[0][ks * 2 + hh][mm][0] = hi8;
        *(short8*)&U.qf[1][ks * 2 + hh][mm][0] = lo8;
    }
    __syncthreads();

    float16 Oa[4];
    float ls[16];
    #pragma unroll
    for (int nt = 0; nt < 4; ++nt)
        #pragma unroll
        for (int r = 0; r < 16; ++r) Oa[nt][r] = 0.f;
    #pragma unroll
    for (int r = 0; r < 16; ++r) ls[r] = 0.f;
    float mrun = NEG_BIG;

    // per-lane Q base byte offset; blinded each iteration so the 16 LDS frag
    // reads are NOT hoisted into 64 registers across the loop
    int qoff = (hf * 32 + m) * 16;

    // ---- K prefetch prologue: first tile's fragments into registers ----
    int4 khb[8], klb[8];
    {
        const size_t tb = ((size_t)(w * 8)) * 512 + ln * 8;   // kt = w (may be > g: unused)
        #pragma unroll
        for (int ks = 0; ks < 8; ++ks) {
            khb[ks] = *(const int4*)(khiH + tb + ks * 512);
            klb[ks] = *(const int4*)(kloH + tb + ks * 512);
        }
    }

    #pragma unroll 1
    for (int kt = w; kt <= g; kt += 4) {               // split-K: wave w owns kt≡w (mod 4)
        asm volatile("" : "+v"(qoff));                 // defeat loop-invariance
        const char* qb0 = (const char*)&U.qf[0][0][0][0] + qoff;

        // ---- QK^T from registers: 8 k-steps x 3 split-MFMAs, TWO chains ----
        float16 accA, accB;
        #pragma unroll
        for (int r = 0; r < 16; ++r) { accA[r] = 0.f; accB[r] = 0.f; }
        #pragma unroll
        for (int ks = 0; ks < 8; ks += 2) {
            union { int4 i4; short8 s; } bhA, blA, qhA, qlA, bhB, blB, qhB, qlB;
            bhA.i4 = khb[ks];     bhB.i4 = khb[ks + 1];
            blA.i4 = klb[ks];     blB.i4 = klb[ks + 1];
            qhA.i4 = *(const int4*)(qb0 + ks * 1024);
            qhB.i4 = *(const int4*)(qb0 + (ks + 1) * 1024);
            qlA.i4 = *(const int4*)(qb0 + 8192 + ks * 1024);
            qlB.i4 = *(const int4*)(qb0 + 8192 + (ks + 1) * 1024);
            accA = __builtin_amdgcn_mfma_f32_32x32x16_bf16(qhA.s, bhA.s, accA, 0, 0, 0);
            accB = __builtin_amdgcn_mfma_f32_32x32x16_bf16(qhB.s, bhB.s, accB, 0, 0, 0);
            accA = __builtin_amdgcn_mfma_f32_32x32x16_bf16(qlA.s, bhA.s, accA, 0, 0, 0);
            accB = __builtin_amdgcn_mfma_f32_32x32x16_bf16(qlB.s, bhB.s, accB, 0, 0, 0);
            accA = __builtin_amdgcn_mfma_f32_32x32x16_bf16(qhA.s, blA.s, accA, 0, 0, 0);
            accB = __builtin_amdgcn_mfma_f32_32x32x16_bf16(qhB.s, blB.s, accB, 0, 0, 0);
        }
        float16 acc;
        #pragma unroll
        for (int r = 0; r < 16; ++r) acc[r] = accA[r] + accB[r];

        // ---- cross-tile K prefetch: next tile's frags into the same regs;
        // L2 latency hides under softmax+PV. Last iteration: clamped reload.
        {
            const int ktn = (kt + 4 <= g) ? (kt + 4) : kt;
            const size_t tbn = ((size_t)(ktn * 8)) * 512 + ln * 8;
            #pragma unroll
            for (int ks = 0; ks < 8; ++ks) {
                khb[ks] = *(const int4*)(khiH + tbn + ks * 512);
                klb[ks] = *(const int4*)(kloH + tbn + ks * 512);
            }
        }

        // V fragment preload: issued here so softmax hides the L2 latency
        int4 vb[8];
        #pragma unroll
        for (int u = 0; u < 8; ++u)
            vb[u] = *(const int4*)(vtH + ((size_t)(kt * 8 + u)) * 512 + ln * 8);

        // causal mask: only the diagonal tile (owned by wave g%4)
        if (kt == g) {
            #pragma unroll
            for (int r = 0; r < 16; ++r)
                if (m > 4 * hf + (r & 3) + 8 * (r >> 2)) acc[r] = NEG_BIG;
        }

        // ---- tile-max online softmax (wave-uniform m) ----
        float tm = acc[0];
        #pragma unroll
        for (int r = 1; r < 16; ++r) tm = fmaxf(tm, acc[r]);
        #pragma unroll
        for (int off = 32; off > 0; off >>= 1)
            tm = fmaxf(tm, __shfl_xor(tm, off, 64));
        const float mnew  = fmaxf(mrun, tm);
        const float alpha = __expf(mrun - mnew);       // first tile: 0
        mrun = mnew;
        if (alpha != 1.0f) {                           // wave-uniform branch
            #pragma unroll
            for (int r = 0; r < 16; ++r) {
                Oa[0][r] *= alpha; Oa[1][r] *= alpha;
                Oa[2][r] *= alpha; Oa[3][r] *= alpha;
                ls[r]    *= alpha;
            }
        }
        #pragma unroll
        for (int r = 0; r < 16; ++r) {
            const float p = __expf(acc[r] - mnew);     // masked -> 0
            ls[r] += p;
            Pl[w][(r & 3) + 8 * (r >> 2) + 4 * hf][m] = bf16_rne(p);
        }
        // no barrier: Pl slab is wave-private; same-wave DS ops are ordered

        // ---- PV (verified math) ----
        #pragma unroll
        for (int ks2 = 0; ks2 < 2; ++ks2) {
            union { int2 d[2]; short8 s; } up;
            const int pe = ks2 * 16 + hf * 8;
            up.d[0] = *(const int2*)&Pl[w][m][pe];
            up.d[1] = *(const int2*)&Pl[w][m][pe + 4];
            #pragma unroll
            for (int nt = 0; nt < 4; ++nt) {
                union { int4 i4; short8 s; } uv;
                uv.i4 = vb[nt * 2 + ks2];
                Oa[nt] = __builtin_amdgcn_mfma_f32_32x32x16_bf16(up.s, uv.s, Oa[nt], 0, 0, 0);
            }
        }
    }

    // ---- per-wave l reduce over the 32 key columns ----
    #pragma unroll
    for (int r = 0; r < 16; ++r) {
        float s = ls[r];
        #pragma unroll
        for (int off = 16; off > 0; off >>= 1)
            s += __shfl_xor(s, off, 64);
        ls[r] = s;
    }
    if (m == 0) {
        #pragma unroll
        for (int r = 0; r < 16; ++r)
            Lw[w][4 * hf + (r & 3) + 8 * (r >> 2)] = ls[r];
    }
    if (ln == 0) Mw[w] = mrun;                         // idle wave (w>g): NEG_BIG
    __syncthreads();                                   // qf dead from here; oc alive

    // ---- flash-decoding combine across the 4 split-K waves, 32-dim chunks ----
    const int crow = t >> 3, c0 = (t & 7) * 4;
    const float M = fmaxf(fmaxf(Mw[0], Mw[1]), fmaxf(Mw[2], Mw[3]));
    float ee[4];
    #pragma unroll
    for (int u = 0; u < 4; ++u) ee[u] = __expf(Mw[u] - M);  // idle wave -> 0
    const float L = ee[0] * Lw[0][crow] + ee[1] * Lw[1][crow]
                  + ee[2] * Lw[2][crow] + ee[3] * Lw[3][crow];
    const float inv = 1.f / L;
    float* op = out + ((size_t)(h * TT + growb + crow)) * DD;

    #pragma unroll
    for (int nt = 0; nt < 4; ++nt) {
        __syncthreads();                               // OC free for this chunk
        #pragma unroll
        for (int r = 0; r < 16; ++r)
            U.oc[w][4 * hf + (r & 3) + 8 * (r >> 2)][m] = Oa[nt][r];
        __syncthreads();                               // chunk visible
        float4 s4 = {0.f, 0.f, 0.f, 0.f};
        #pragma unroll
        for (int u = 0; u < 4; ++u) {
            const float4 ov = *(const float4*)&U.oc[u][crow][c0];
            s4.x += ee[u] * ov.x; s4.y += ee[u] * ov.y;
            s4.z += ee[u] * ov.z; s4.w += ee[u] * ov.w;
        }
        s4.x *= inv; s4.y *= inv; s4.z *= inv; s4.w *= inv;
        *(float4*)(op + nt * 32 + c0) = s4;
    }
}

extern "C" void kernel_launch(void* const* d_in, const int* in_sizes, int n_in,
                              void* d_out, int out_size, void* d_ws, size_t ws_size,
                              hipStream_t stream) {
    const float* q = (const float*)d_in[0];
    const float* k = (const float*)d_in[1];
    const float* v = (const float*)d_in[2];
    float* out = (float*)d_out;

    short* khi = (short*)d_ws;
    short* klo = khi + (size_t)HH * HEAD_FRAG_SHORTS;
    short* vt  = klo + (size_t)HH * HEAD_FRAG_SHORTS;

    prep_kernel<<<dim3(HH, NKT), dim3(256), 0, stream>>>(k, v, khi, klo, vt);
    attn_kernel<<<dim3(HH, NKT), dim3(256), 0, stream>>>(q, khi, klo, vt, out);
}

// Round 8
// 180.679 us; speedup vs baseline: 1.0438x; 1.0438x over previous
//
#include <hip/hip_runtime.h>

#define HH 8
#define TT 4096
#define DD 128
#define NKT 128              // 32-key tiles per head
#define PS 36                // P row stride in shorts (72 B rows)
#define NEG_BIG (-3.0e38f)
#define DEFER_THR 8.0f       // defer-max threshold: P bounded by e^8

// ws (shorts): Khi[8.4MB] | Klo[8.4MB] | Vt[8.4MB]
#define HEAD_FRAG_SHORTS ((size_t)NKT * 8 * 512)

typedef __attribute__((ext_vector_type(8)))  short short8;
typedef __attribute__((ext_vector_type(16))) float float16;

__device__ __forceinline__ short bf16_rne(float x) {
    unsigned u = __float_as_uint(x);
    return (short)((u + 0x7fffu + ((u >> 16) & 1u)) >> 16);
}
__device__ __forceinline__ float bf16_f(short s) {
    return __uint_as_float(((unsigned)(unsigned short)s) << 16);
}

// ---------------- prep: fp32 K,V -> bf16 hi/lo fragments (verified, unchanged) ----------------
__global__ __launch_bounds__(256) void prep_kernel(
    const float* __restrict__ k, const float* __restrict__ v,
    short* __restrict__ khi, short* __restrict__ klo, short* __restrict__ vt)
{
    const int h = blockIdx.x, kt = blockIdx.y, t = threadIdx.x;
    __shared__ float Vs[32][132];

    #pragma unroll
    for (int it = 0; it < 4; ++it) {               // stage V tile 32 keys x 128 dims
        const int f = t + it * 256, j = f >> 5, c = f & 31;
        *(float4*)&Vs[j][c * 4] =
            *(const float4*)(v + ((size_t)(h * TT + kt * 32 + j)) * DD + c * 4);
    }
    // K fragments: B[n=key m][k-dim = ks*16 + hf*8 + e]
    #pragma unroll
    for (int it = 0; it < 2; ++it) {
        const int idx = t + it * 256;
        const int ks = idx >> 6, ln = idx & 63, m = ln & 31, hf = ln >> 5;
        const float* src = k + ((size_t)(h * TT + kt * 32 + m)) * DD + ks * 16 + hf * 8;
        const float4 a = *(const float4*)src;
        const float4 b = *(const float4*)(src + 4);
        const float f8[8] = {a.x, a.y, a.z, a.w, b.x, b.y, b.z, b.w};
        short8 hi8, lo8;
        #pragma unroll
        for (int e = 0; e < 8; ++e) {
            const short hi_ = bf16_rne(f8[e]);
            hi8[e] = hi_;
            lo8[e] = bf16_rne(f8[e] - bf16_f(hi_));
        }
        const size_t off = ((size_t)((h * NKT + kt) * 8 + ks)) * 512 + ln * 8;
        *(short8*)(khi + off) = hi8;
        *(short8*)(klo + off) = lo8;
    }
    __syncthreads();
    // V fragments: B[n=dim nt*32+m][k-key = ks2*16 + hf*8 + e]
    #pragma unroll
    for (int it = 0; it < 2; ++it) {
        const int idx = t + it * 256;
        const int nt = idx >> 7, ks2 = (idx >> 6) & 1, ln = idx & 63;
        const int m = ln & 31, hf = ln >> 5, n = nt * 32 + m;
        short8 o;
        #pragma unroll
        for (int e = 0; e < 8; ++e)
            o[e] = bf16_rne(Vs[ks2 * 16 + hf * 8 + e][n]);
        *(short8*)(vt + ((size_t)(((h * NKT + kt) * 4 + nt) * 2 + ks2)) * 512 + ln * 8) = o;
    }
}

// ------- attention: 4-wave split-K, Q in LDS, dual-chain QK, defer-max -------
// Round-6 structure (112.4µs verified: dual-chain QK, vb preload after QK,
// no K reg-prefetch — round 7 proved it net-negative) + ONE change:
// defer-max softmax (round-4 block verbatim). The 6-step shfl max-reduce
// (~240cy serial ds-permute) + Oa/ls rescale (~160cy, taken nearly every
// tile) run only when __any(lane tm > mrun+8) — ~10% of tiles. P bounded
// by e^8; bf16 precision is scale-invariant; ls/Oa fp32; 1/L cancels scale.
// No setprio (round 5: fences load scheduling at 2 waves/SIMD).
__global__ __launch_bounds__(256, 2) void attn_kernel(
    const float* __restrict__ q,
    const short* __restrict__ khi, const short* __restrict__ klo,
    const short* __restrict__ vt, float* __restrict__ out)
{
    const int h = blockIdx.x;                          // head -> XCD L2 pinning
    const int g = (int)(gridDim.y - 1) - (int)blockIdx.y;  // big row-tiles first
    const int growb = g * 32;
    const int t = threadIdx.x, w = t >> 6, ln = t & 63, m = ln & 31, hf = ln >> 5;

    // qf lifetime: staging + kt loop. oc lifetime: combine (after barrier). Union ok.
    __shared__ union {
        short qf[2][16][32][8];                        // 16 KB [hi/lo][ks*2+hf][m][e]
        float oc[4][32][36];                           // 18.4 KB combine chunks
    } U;
    __shared__ short Pl[4][32][PS];                    // wave-private P slabs (9.2 KB)
    __shared__ float Lw[4][32];
    __shared__ float Mw[4];

    const short* khiH = khi + (size_t)h * HEAD_FRAG_SHORTS;
    const short* kloH = klo + (size_t)h * HEAD_FRAG_SHORTS;
    const short* vtH  = vt  + (size_t)h * HEAD_FRAG_SHORTS;

    // ---- stage Q (32 rows) as bf16 hi/lo A-fragments into LDS (once per block)
    #pragma unroll
    for (int it = 0; it < 2; ++it) {
        const int idx = t + it * 256;                  // 512 fragments: ks*2*32 + hf*32 + m
        const int ks = idx >> 6, l2 = idx & 63, mm = l2 & 31, hh = l2 >> 5;
        const float* src = q + ((size_t)(h * TT + growb + mm)) * DD + ks * 16 + hh * 8;
        const float4 a = *(const float4*)src;
        const float4 b = *(const float4*)(src + 4);
        const float f8[8] = {a.x, a.y, a.z, a.w, b.x, b.y, b.z, b.w};
        short8 hi8, lo8;
        #pragma unroll
        for (int e = 0; e < 8; ++e) {
            const short hi_ = bf16_rne(f8[e]);
            hi8[e] = hi_;
            lo8[e] = bf16_rne(f8[e] - bf16_f(hi_));
        }
        *(short8*)&U.qf[0][ks * 2 + hh][mm][0] = hi8;
        *(short8*)&U.qf[1][ks * 2 + hh][mm][0] = lo8;
    }
    __syncthreads();

    float16 Oa[4];
    float ls[16];
    #pragma unroll
    for (int nt = 0; nt < 4; ++nt)
        #pragma unroll
        for (int r = 0; r < 16; ++r) Oa[nt][r] = 0.f;
    #pragma unroll
    for (int r = 0; r < 16; ++r) ls[r] = 0.f;
    float mrun = NEG_BIG;

    // per-lane Q base byte offset; blinded each iteration so the 16 LDS frag
    // reads are NOT hoisted into 64 registers across the loop
    int qoff = (hf * 32 + m) * 16;

    #pragma unroll 1
    for (int kt = w; kt <= g; kt += 4) {               // split-K: wave w owns kt≡w (mod 4)
        asm volatile("" : "+v"(qoff));                 // defeat loop-invariance
        const char* qb0 = (const char*)&U.qf[0][0][0][0] + qoff;

        // ---- QK^T: 8 k-steps x 3 split-MFMAs, TWO independent acc chains ----
        float16 accA, accB;
        #pragma unroll
        for (int r = 0; r < 16; ++r) { accA[r] = 0.f; accB[r] = 0.f; }
        #pragma unroll
        for (int ks = 0; ks < 8; ks += 2) {
            union { int4 i4; short8 s; } bhA, blA, qhA, qlA, bhB, blB, qhB, qlB;
            const size_t foA = ((size_t)(kt * 8 + ks)) * 512 + ln * 8;
            const size_t foB = ((size_t)(kt * 8 + ks + 1)) * 512 + ln * 8;
            bhA.i4 = *(const int4*)(khiH + foA);
            bhB.i4 = *(const int4*)(khiH + foB);
            blA.i4 = *(const int4*)(kloH + foA);
            blB.i4 = *(const int4*)(kloH + foB);
            qhA.i4 = *(const int4*)(qb0 + ks * 1024);
            qhB.i4 = *(const int4*)(qb0 + (ks + 1) * 1024);
            qlA.i4 = *(const int4*)(qb0 + 8192 + ks * 1024);
            qlB.i4 = *(const int4*)(qb0 + 8192 + (ks + 1) * 1024);
            accA = __builtin_amdgcn_mfma_f32_32x32x16_bf16(qhA.s, bhA.s, accA, 0, 0, 0);
            accB = __builtin_amdgcn_mfma_f32_32x32x16_bf16(qhB.s, bhB.s, accB, 0, 0, 0);
            accA = __builtin_amdgcn_mfma_f32_32x32x16_bf16(qlA.s, bhA.s, accA, 0, 0, 0);
            accB = __builtin_amdgcn_mfma_f32_32x32x16_bf16(qlB.s, bhB.s, accB, 0, 0, 0);
            accA = __builtin_amdgcn_mfma_f32_32x32x16_bf16(qhA.s, blA.s, accA, 0, 0, 0);
            accB = __builtin_amdgcn_mfma_f32_32x32x16_bf16(qhB.s, blB.s, accB, 0, 0, 0);
        }
        float16 acc;
        #pragma unroll
        for (int r = 0; r < 16; ++r) acc[r] = accA[r] + accB[r];

        // V fragment preload: issued here so softmax hides the L2 latency
        int4 vb[8];
        #pragma unroll
        for (int u = 0; u < 8; ++u)
            vb[u] = *(const int4*)(vtH + ((size_t)(kt * 8 + u)) * 512 + ln * 8);

        // causal mask: only the diagonal tile (owned by wave g%4)
        if (kt == g) {
            #pragma unroll
            for (int r = 0; r < 16; ++r)
                if (m > 4 * hf + (r & 3) + 8 * (r >> 2)) acc[r] = NEG_BIG;
        }

        // ---- defer-max online softmax: full reduce+rescale only when needed ----
        float tm = acc[0];
        #pragma unroll
        for (int r = 1; r < 16; ++r) tm = fmaxf(tm, acc[r]);
        if (__any(tm > mrun + DEFER_THR)) {            // wave-uniform trigger
            float tw = tm;
            #pragma unroll
            for (int off = 32; off > 0; off >>= 1)
                tw = fmaxf(tw, __shfl_xor(tw, off, 64));
            const float mnew  = fmaxf(mrun, tw);
            const float alpha = __expf(mrun - mnew);   // first tile: 0
            #pragma unroll
            for (int r = 0; r < 16; ++r) {
                Oa[0][r] *= alpha; Oa[1][r] *= alpha;
                Oa[2][r] *= alpha; Oa[3][r] *= alpha;
                ls[r]    *= alpha;
            }
            mrun = mnew;
        }
        #pragma unroll
        for (int r = 0; r < 16; ++r) {
            const float p = __expf(acc[r] - mrun);     // bounded by e^8; masked -> 0
            ls[r] += p;
            Pl[w][(r & 3) + 8 * (r >> 2) + 4 * hf][m] = bf16_rne(p);
        }
        // no barrier: Pl slab is wave-private; same-wave DS ops are ordered

        // ---- PV (verified math) ----
        #pragma unroll
        for (int ks2 = 0; ks2 < 2; ++ks2) {
            union { int2 d[2]; short8 s; } up;
            const int pe = ks2 * 16 + hf * 8;
            up.d[0] = *(const int2*)&Pl[w][m][pe];
            up.d[1] = *(const int2*)&Pl[w][m][pe + 4];
            #pragma unroll
            for (int nt = 0; nt < 4; ++nt) {
                union { int4 i4; short8 s; } uv;
                uv.i4 = vb[nt * 2 + ks2];
                Oa[nt] = __builtin_amdgcn_mfma_f32_32x32x16_bf16(up.s, uv.s, Oa[nt], 0, 0, 0);
            }
        }
    }

    // ---- per-wave l reduce over the 32 key columns ----
    #pragma unroll
    for (int r = 0; r < 16; ++r) {
        float s = ls[r];
        #pragma unroll
        for (int off = 16; off > 0; off >>= 1)
            s += __shfl_xor(s, off, 64);
        ls[r] = s;
    }
    if (m == 0) {
        #pragma unroll
        for (int r = 0; r < 16; ++r)
            Lw[w][4 * hf + (r & 3) + 8 * (r >> 2)] = ls[r];
    }
    if (ln == 0) Mw[w] = mrun;                         // idle wave (w>g): NEG_BIG
    __syncthreads();                                   // qf dead from here; oc alive

    // ---- flash-decoding combine across the 4 split-K waves, 32-dim chunks ----
    const int crow = t >> 3, c0 = (t & 7) * 4;
    const float M = fmaxf(fmaxf(Mw[0], Mw[1]), fmaxf(Mw[2], Mw[3]));
    float ee[4];
    #pragma unroll
    for (int u = 0; u < 4; ++u) ee[u] = __expf(Mw[u] - M);  // idle wave -> 0
    const float L = ee[0] * Lw[0][crow] + ee[1] * Lw[1][crow]
                  + ee[2] * Lw[2][crow] + ee[3] * Lw[3][crow];
    const float inv = 1.f / L;
    float* op = out + ((size_t)(h * TT + growb + crow)) * DD;

    #pragma unroll
    for (int nt = 0; nt < 4; ++nt) {
        __syncthreads();                               // OC free for this chunk
        #pragma unroll
        for (int r = 0; r < 16; ++r)
            U.oc[w][4 * hf + (r & 3) + 8 * (r >> 2)][m] = Oa[nt][r];
        __syncthreads();                               // chunk visible
        float4 s4 = {0.f, 0.f, 0.f, 0.f};
        #pragma unroll
        for (int u = 0; u < 4; ++u) {
            const float4 ov = *(const float4*)&U.oc[u][crow][c0];
            s4.x += ee[u] * ov.x; s4.y += ee[u] * ov.y;
            s4.z += ee[u] * ov.z; s4.w += ee[u] * ov.w;
        }
        s4.x *= inv; s4.y *= inv; s4.z *= inv; s4.w *= inv;
        *(float4*)(op + nt * 32 + c0) = s4;
    }
}

extern "C" void kernel_launch(void* const* d_in, const int* in_sizes, int n_in,
                              void* d_out, int out_size, void* d_ws, size_t ws_size,
                              hipStream_t stream) {
    const float* q = (const float*)d_in[0];
    const float* k = (const float*)d_in[1];
    const float* v = (const float*)d_in[2];
    float* out = (float*)d_out;

    short* khi = (short*)d_ws;
    short* klo = khi + (size_t)HH * HEAD_FRAG_SHORTS;
    short* vt  = klo + (size_t)HH * HEAD_FRAG_SHORTS;

    prep_kernel<<<dim3(HH, NKT), dim3(256), 0, stream>>>(k, v, khi, klo, vt);
    attn_kernel<<<dim3(HH, NKT), dim3(256), 0, stream>>>(q, khi, klo, vt, out);
}